// Round 1
// baseline (1233.879 us; speedup 1.0000x reference)
//
#include <hip/hip_runtime.h>
#include <math.h>

#define B_  2
#define S_  1024
#define H_  2048
#define F_  512          // H/4
#define KD_ 32
#define NC_ 16
#define M_  (B_ * S_)    // 2048 tokens

// ---------------------------------------------------------------------------
// K0: x_pooled[b,h] = mean over s of x[b,s,h]
// grid 16 blocks (b = blk>>3, 256-col chunk = blk&7), 256 threads
// ---------------------------------------------------------------------------
__global__ __launch_bounds__(256) void pool_kernel(const float* __restrict__ x,
                                                   float* __restrict__ xp) {
    int b = blockIdx.x >> 3;
    int h = ((blockIdx.x & 7) << 8) + threadIdx.x;
    const float* p = x + (size_t)b * S_ * H_ + h;
    float s = 0.f;
    for (int i = 0; i < S_; ++i) s += p[(size_t)i * H_];
    xp[b * H_ + h] = s * (1.0f / S_);
}

// ---------------------------------------------------------------------------
// K1: cache-lookup decision (hit/best) + complexity-estimator rank_idx.
// Single block, 256 threads.
// flags: [0]=n_crit (memset elsewhere) [1]=rank_idx [2]=hit [3]=best
// ---------------------------------------------------------------------------
__global__ __launch_bounds__(256) void decide_kernel(
    const float* __restrict__ xp, const float* __restrict__ kpw,
    const float* __restrict__ ck,
    const float* __restrict__ cw1, const float* __restrict__ cb1,
    const float* __restrict__ cw2, const float* __restrict__ cb2,
    int* __restrict__ flags) {
    __shared__ float qk_s[B_ * KD_];   // 64
    __shared__ float ce_s[B_ * 64];    // 128
    int tid = threadIdx.x;
    // qk = x_pooled @ key_proj_w.T  (64 outputs, 4 threads each over K=2048)
    {
        int out = tid >> 2, part = tid & 3;
        int b = out >> 5, d = out & 31;
        const float* xr = xp + b * H_;
        const float* wr = kpw + (size_t)d * H_;
        float s = 0.f;
        int k0 = part * 512;
        for (int k = 0; k < 512; ++k) s += xr[k0 + k] * wr[k0 + k];
        s += __shfl_down(s, 2, 4);
        s += __shfl_down(s, 1, 4);
        if (part == 0) qk_s[out] = s;
    }
    // ce_h = relu(x_pooled @ ce_w1.T + ce_b1)  (128 outputs, K=2048)
    if (tid < 128) {
        int b = tid >> 6, j = tid & 63;
        const float* xr = xp + b * H_;
        const float* wr = cw1 + (size_t)j * H_;
        float s = cb1[j];
        for (int k = 0; k < H_; ++k) s += xr[k] * wr[k];
        ce_s[tid] = fmaxf(s, 0.f);
    }
    __syncthreads();
    if (tid == 0) {
        // normalize qk per batch row, then global-flat cosine vs cache keys
        float qf[B_ * KD_];
        for (int b = 0; b < B_; ++b) {
            float nn = 0.f;
            for (int d = 0; d < KD_; ++d) { float v = qk_s[b * KD_ + d]; nn += v * v; }
            float den = fmaxf(sqrtf(nn), 1e-8f);
            for (int d = 0; d < KD_; ++d) qf[b * KD_ + d] = qk_s[b * KD_ + d] / den;
        }
        float qn = 0.f;
        for (int i = 0; i < B_ * KD_; ++i) qn += qf[i] * qf[i];
        float qnorm = fmaxf(sqrtf(qn), 1e-8f);
        float bestv = -1e30f; int best = 0;
        for (int n = 0; n < NC_; ++n) {
            float dot = 0.f, nn = 0.f;
            for (int i = 0; i < B_ * KD_; ++i) {
                float c = ck[n * (B_ * KD_) + i];
                dot += c * qf[i]; nn += c * c;
            }
            float sim = dot / (fmaxf(sqrtf(nn), 1e-8f) * qnorm);
            if (sim > bestv) { bestv = sim; best = n; }
        }
        flags[2] = (bestv >= 0.95f) ? 1 : 0;
        flags[3] = best;
        // scores = ce_h @ ce_w2.T + ce_b2 ; flat argmax % 4
        float bs = -1e30f; int bi = 0;
        for (int b = 0; b < B_; ++b)
            for (int o = 0; o < 4; ++o) {
                float v = cb2[o];
                for (int j = 0; j < 64; ++j) v += ce_s[b * 64 + j] * cw2[o * 64 + j];
                int idx = b * 4 + o;
                if (v > bs) { bs = v; bi = idx; }
            }
        flags[1] = bi & 3;
    }
}

// ---------------------------------------------------------------------------
// Generic fp32 NT GEMM: C[m,n] = sum_k A[m,k] * B[n,k]  (+bias, optional relu)
// A row-major [M,K], B row-major [N,K], C row-major ldc.
// Optional: gather (row indices for A load AND C store), count_ptr (dynamic M),
// rank_ptr (select B among Bu0..3 and N among {4,12,40,128}).
// Tile 64x64, BK=16, 256 threads, 4x4 per thread. K must be %16, rows 16B-aligned.
// ---------------------------------------------------------------------------
__global__ __launch_bounds__(256) void gemm_nt(
    const float* __restrict__ A,
    const float* __restrict__ Bu0, const float* __restrict__ Bu1,
    const float* __restrict__ Bu2, const float* __restrict__ Bu3,
    float* __restrict__ C, int M, int N, int K, int ldc,
    const float* __restrict__ bias, int relu,
    const int* __restrict__ gather, const int* __restrict__ count_ptr,
    const int* __restrict__ rank_ptr) {
    __shared__ float As[16][68];
    __shared__ float Bs[16][68];
    const float* Bp = Bu0;
    if (rank_ptr) {
        int r = *rank_ptr;
        Bp = (r == 0) ? Bu0 : (r == 1) ? Bu1 : (r == 2) ? Bu2 : Bu3;
        N  = (r == 0) ? 4   : (r == 1) ? 12  : (r == 2) ? 40  : 128;
    }
    if (count_ptr) M = *count_ptr;
    int m0 = blockIdx.x << 6, n0 = blockIdx.y << 6;
    if (m0 >= M || n0 >= N) return;
    int tid = threadIdx.x;
    int lr = tid >> 2;            // 0..63 (tile row for load)
    int lk = (tid & 3) << 2;      // 0,4,8,12
    bool avalid = (m0 + lr) < M;
    int arow = avalid ? (gather ? gather[m0 + lr] : (m0 + lr)) : 0;
    const float* aptr = A + (size_t)arow * K + lk;
    bool bvalid = (n0 + lr) < N;
    const float* bptr = Bp + (size_t)(bvalid ? (n0 + lr) : 0) * K + lk;
    int tx = tid & 15, ty = tid >> 4;
    float acc[4][4];
#pragma unroll
    for (int i = 0; i < 4; ++i)
#pragma unroll
        for (int j = 0; j < 4; ++j) acc[i][j] = 0.f;

    for (int k0 = 0; k0 < K; k0 += 16) {
        float4 a4 = avalid ? *(const float4*)(aptr + k0) : make_float4(0.f, 0.f, 0.f, 0.f);
        float4 b4 = bvalid ? *(const float4*)(bptr + k0) : make_float4(0.f, 0.f, 0.f, 0.f);
        __syncthreads();
        As[lk + 0][lr] = a4.x; As[lk + 1][lr] = a4.y;
        As[lk + 2][lr] = a4.z; As[lk + 3][lr] = a4.w;
        Bs[lk + 0][lr] = b4.x; Bs[lk + 1][lr] = b4.y;
        Bs[lk + 2][lr] = b4.z; Bs[lk + 3][lr] = b4.w;
        __syncthreads();
#pragma unroll
        for (int kk = 0; kk < 16; ++kk) {
            const float4 av = *(const float4*)&As[kk][ty << 2];
            const float4 bv = *(const float4*)&Bs[kk][tx << 2];
            float a[4] = {av.x, av.y, av.z, av.w};
            float b[4] = {bv.x, bv.y, bv.z, bv.w};
#pragma unroll
            for (int i = 0; i < 4; ++i)
#pragma unroll
                for (int j = 0; j < 4; ++j) acc[i][j] += a[i] * b[j];
        }
    }
#pragma unroll
    for (int i = 0; i < 4; ++i) {
        int mi = m0 + (ty << 2) + i;
        if (mi >= M) break;
        int orow = gather ? gather[mi] : mi;
        float* crow = C + (size_t)orow * ldc;
#pragma unroll
        for (int j = 0; j < 4; ++j) {
            int c = n0 + (tx << 2) + j;
            if (c < N) {
                float v = acc[i][j];
                if (bias) v += bias[c];
                if (relu) v = fmaxf(v, 0.f);
                crow[c] = v;
            }
        }
    }
}

// ---------------------------------------------------------------------------
// K3: content -> imp -> route; append critical tokens to clist (flags[0]).
// grid 512 blocks x 256 threads; one token per wave.
// ---------------------------------------------------------------------------
__global__ __launch_bounds__(256) void score_route_kernel(
    const float* __restrict__ h, const float* __restrict__ w2,
    const float* __restrict__ b2, const float* __restrict__ pos,
    int* __restrict__ flags, int* __restrict__ route, int* __restrict__ clist) {
    int tid = threadIdx.x;
    int m = (blockIdx.x << 2) + (tid >> 6);
    int lane = tid & 63;
    const float* hr = h + (size_t)m * F_;
    float s = 0.f;
    for (int f = lane; f < F_; f += 64) s += hr[f] * w2[f];
    for (int off = 32; off > 0; off >>= 1) s += __shfl_down(s, off, 64);
    if (lane == 0) {
        float content = s + b2[0];
        int si = m & (S_ - 1);
        float imp = 1.0f / (1.0f + expf(-(content + 0.1f * pos[si])));
        if (si == 0 || si == S_ - 1) imp *= 2.0f;
        int rt = (imp > 0.8f) ? 0 : ((imp < 0.3f) ? 1 : 2);
        route[m] = rt;
        if (rt == 0) {
            int idx = atomicAdd(&flags[0], 1);
            clist[idx] = m;
        }
    }
}

// ---------------------------------------------------------------------------
// K6/K7: stage-2 low-rank apply + routing epilogue for one class.
// cls==1 (simple): out = x + (hit ? cache_delta[best] : t4 @ v4^T)
// cls==2 (normal): out = x + tr @ v_rank^T
// Block: 16 tokens x all 2048 cols. grid 128 blocks.
// ---------------------------------------------------------------------------
__global__ __launch_bounds__(256) void stage2_kernel(
    int cls, const float* __restrict__ x,
    const float* __restrict__ t4p, const float* __restrict__ trp,
    const float* __restrict__ v4, const float* __restrict__ v12,
    const float* __restrict__ v40, const float* __restrict__ v128,
    const float* __restrict__ cd, const int* __restrict__ flags,
    const int* __restrict__ route, float* __restrict__ out) {
    __shared__ float Ts[16][132];
    __shared__ int act[16];
    int tid = threadIdx.x;
    int m0 = blockIdx.x << 4;

    const float* V; int Kr; const float* T; int ldt;
    if (cls == 1) { V = v4; Kr = 4; T = t4p; ldt = 4; }
    else {
        int r = flags[1];
        V  = (r == 0) ? v4 : (r == 1) ? v12 : (r == 2) ? v40 : v128;
        Kr = (r == 0) ? 4  : (r == 1) ? 12  : (r == 2) ? 40  : 128;
        T = trp; ldt = 128;
    }
    int hit = flags[2], best = flags[3];

    if (tid < 16) act[tid] = (route[m0 + tid] == cls) ? 1 : 0;
    for (int idx = tid; idx < 16 * Kr; idx += 256) {
        int i = idx / Kr, j = idx - i * Kr;
        Ts[i][j] = T[(size_t)(m0 + i) * ldt + j];
    }
    __syncthreads();

    bool use_delta = (cls == 1) && hit;
    for (int c = tid; c < H_; c += 256) {
        float acc[16];
#pragma unroll
        for (int i = 0; i < 16; ++i) acc[i] = 0.f;
        if (!use_delta) {
            const float* vrow = V + (size_t)c * Kr;
            for (int j = 0; j < Kr; j += 4) {
                const float4 vv = *(const float4*)(vrow + j);
#pragma unroll
                for (int i = 0; i < 16; ++i) {
                    const float4 tv = *(const float4*)&Ts[i][j];
                    acc[i] += tv.x * vv.x + tv.y * vv.y + tv.z * vv.z + tv.w * vv.w;
                }
            }
        }
#pragma unroll
        for (int i = 0; i < 16; ++i) {
            if (act[i]) {
                size_t off = (size_t)(m0 + i) * H_ + c;
                float upd = use_delta
                    ? cd[(size_t)best * (size_t)(B_ * S_ * H_) + off]
                    : acc[i];
                out[off] = x[off] + upd;
            }
        }
    }
}

// ---------------------------------------------------------------------------
extern "C" void kernel_launch(void* const* d_in, const int* in_sizes, int n_in,
                              void* d_out, int out_size, void* d_ws, size_t ws_size,
                              hipStream_t stream) {
    const float* x    = (const float*)d_in[0];
    const float* sw1  = (const float*)d_in[1];
    const float* sb1  = (const float*)d_in[2];
    const float* sw2  = (const float*)d_in[3];
    const float* sb2  = (const float*)d_in[4];
    const float* pos  = (const float*)d_in[5];
    const float* kpw  = (const float*)d_in[6];
    const float* ck   = (const float*)d_in[7];
    const float* cd   = (const float*)d_in[8];
    const float* cw1  = (const float*)d_in[9];
    const float* cb1  = (const float*)d_in[10];
    const float* cw2  = (const float*)d_in[11];
    const float* cb2  = (const float*)d_in[12];
    const float* u4   = (const float*)d_in[13];
    const float* v4   = (const float*)d_in[14];
    const float* u12  = (const float*)d_in[15];
    const float* v12  = (const float*)d_in[16];
    const float* u40  = (const float*)d_in[17];
    const float* v40  = (const float*)d_in[18];
    const float* u128 = (const float*)d_in[19];
    const float* v128 = (const float*)d_in[20];
    const float* lw   = (const float*)d_in[21];
    const float* lb   = (const float*)d_in[22];
    float* out = (float*)d_out;

    // workspace layout (fp32 unless noted)
    float* xp    = (float*)d_ws;            // [B,H]      4096
    float* t4p   = xp + B_ * H_;            // [M,4]      8192
    float* trp   = t4p + M_ * 4;            // [M,128]    262144
    int*   flags = (int*)(trp + M_ * 128);  // [0]=n_crit [1]=rank [2]=hit [3]=best
    int*   route = flags + 8;               // [M]
    int*   clist = route + M_;              // [M]
    // scorer hidden h [M,F] lives in d_out's first 4MB: consumed by
    // score_route before any output row is written; every output element is
    // overwritten afterwards by exactly one of {critical gemm, stage2 cls1/2}.
    float* hbuf = out;

    hipMemsetAsync(flags, 0, sizeof(int), stream);   // n_crit = 0

    pool_kernel<<<16, 256, 0, stream>>>(x, xp);
    decide_kernel<<<1, 256, 0, stream>>>(xp, kpw, ck, cw1, cb1, cw2, cb2, flags);

    // scorer: h = relu(x @ sw1^T + sb1)   [2048 x 512]
    gemm_nt<<<dim3(32, 8), 256, 0, stream>>>(
        x, sw1, nullptr, nullptr, nullptr, hbuf, M_, F_, H_, F_,
        sb1, 1, nullptr, nullptr, nullptr);

    score_route_kernel<<<512, 256, 0, stream>>>(hbuf, sw2, sb2, pos, flags, route, clist);

    // t4 = x @ u4^T   [2048 x 4]
    gemm_nt<<<dim3(32, 1), 256, 0, stream>>>(
        x, u4, nullptr, nullptr, nullptr, t4p, M_, 4, H_, 4,
        nullptr, 0, nullptr, nullptr, nullptr);

    // tr = x @ u_rank^T   [2048 x r] (rank selected on device)
    gemm_nt<<<dim3(32, 2), 256, 0, stream>>>(
        x, u4, u12, u40, u128, trp, M_, 128, H_, 128,
        nullptr, 0, nullptr, nullptr, &flags[1]);

    // critical rows: out[row] = x[row] @ lw^T + lb  (gathered, dynamic M)
    gemm_nt<<<dim3(32, 32), 256, 0, stream>>>(
        x, lw, nullptr, nullptr, nullptr, out, M_, H_, H_, H_,
        lb, 0, clist, &flags[0], nullptr);

    // simple rows
    stage2_kernel<<<128, 256, 0, stream>>>(
        1, x, t4p, trp, v4, v12, v40, v128, cd, flags, route, out);
    // normal rows
    stage2_kernel<<<128, 256, 0, stream>>>(
        2, x, t4p, trp, v4, v12, v40, v128, cd, flags, route, out);
}

// Round 2
// 911.489 us; speedup vs baseline: 1.3537x; 1.3537x over previous
//
#include <hip/hip_runtime.h>
#include <math.h>

#define B_  2
#define S_  1024
#define H_  2048
#define F_  512          // H/4
#define KD_ 32
#define NC_ 16
#define M_  (B_ * S_)    // 2048 tokens

typedef __attribute__((ext_vector_type(8))) short bf16x8;
typedef __attribute__((ext_vector_type(4))) float f32x4;

__device__ __forceinline__ ushort f2bf(float f) {
    unsigned u = __float_as_uint(f);
    u += 0x7FFFu + ((u >> 16) & 1u);   // RNE
    return (ushort)(u >> 16);
}

// ---------------------------------------------------------------------------
// Pooling, two stage: partial[b*16+seg][col] = sum of 64 rows; then finalize.
// ---------------------------------------------------------------------------
__global__ __launch_bounds__(256) void pool_partial_kernel(
    const float* __restrict__ x, float* __restrict__ partial) {
    int blk = blockIdx.x;              // 256 blocks
    int b = blk >> 7, rem = blk & 127;
    int seg = rem >> 3, chunk = rem & 7;
    int col = (chunk << 8) + threadIdx.x;
    const float* p = x + (size_t)b * S_ * H_ + (size_t)(seg << 6) * H_ + col;
    float s = 0.f;
    for (int i = 0; i < 64; ++i) s += p[(size_t)i * H_];
    partial[(size_t)(b * 16 + seg) * H_ + col] = s;
}

__global__ __launch_bounds__(256) void pool_final_kernel(
    const float* __restrict__ partial, float* __restrict__ xp) {
    int b = blockIdx.x >> 3, chunk = blockIdx.x & 7;   // 16 blocks
    int col = (chunk << 8) + threadIdx.x;
    float s = 0.f;
    for (int seg = 0; seg < 16; ++seg)
        s += partial[(size_t)(b * 16 + seg) * H_ + col];
    xp[b * H_ + col] = s * (1.0f / S_);
}

// ---------------------------------------------------------------------------
// Decision kernel: cache hit/best + rank_idx. Single block, 256 threads.
// flags: [0]=n_crit (memset before) [1]=rank_idx [2]=hit [3]=best
// ---------------------------------------------------------------------------
__global__ __launch_bounds__(256) void decide_kernel(
    const float* __restrict__ xp, const float* __restrict__ kpw,
    const float* __restrict__ ck,
    const float* __restrict__ cw1, const float* __restrict__ cb1,
    const float* __restrict__ cw2, const float* __restrict__ cb2,
    int* __restrict__ flags) {
    __shared__ float qk_s[B_ * KD_];   // 64
    __shared__ float ce_s[B_ * 64];    // 128
    __shared__ float sims_s[NC_];
    __shared__ float sc_s[8];
    __shared__ float qn_s;
    int tid = threadIdx.x;
    // qk = x_pooled @ key_proj_w.T  (64 outputs, 4 threads each over K=2048)
    {
        int out = tid >> 2, part = tid & 3;
        int b = out >> 5, d = out & 31;
        const float* xr = xp + b * H_;
        const float* wr = kpw + (size_t)d * H_;
        float s = 0.f;
        int k0 = part * 512;
        for (int k = 0; k < 512; ++k) s += xr[k0 + k] * wr[k0 + k];
        s += __shfl_down(s, 2, 4);
        s += __shfl_down(s, 1, 4);
        if (part == 0) qk_s[out] = s;
    }
    // ce_h = relu(x_pooled @ ce_w1.T + ce_b1)  (128 outputs, 2 threads each)
    {
        int out = tid >> 1, half = tid & 1;
        int b = out >> 6, j = out & 63;
        const float* xr = xp + b * H_ + half * 1024;
        const float* wr = cw1 + (size_t)j * H_ + half * 1024;
        float s = 0.f;
        for (int k = 0; k < 1024; ++k) s += xr[k] * wr[k];
        s += __shfl_down(s, 1, 2);
        if (half == 0) ce_s[out] = fmaxf(s + cb1[j], 0.f);
    }
    __syncthreads();
    if (tid == 0) {
        for (int b = 0; b < B_; ++b) {
            float nn = 0.f;
            for (int d = 0; d < KD_; ++d) { float v = qk_s[b * KD_ + d]; nn += v * v; }
            float den = fmaxf(sqrtf(nn), 1e-8f);
            for (int d = 0; d < KD_; ++d) qk_s[b * KD_ + d] /= den;
        }
        float qn = 0.f;
        for (int i = 0; i < B_ * KD_; ++i) qn += qk_s[i] * qk_s[i];
        qn_s = fmaxf(sqrtf(qn), 1e-8f);
    }
    __syncthreads();
    if (tid < NC_) {
        float dot = 0.f, nn = 0.f;
        for (int i = 0; i < B_ * KD_; ++i) {
            float c = ck[tid * (B_ * KD_) + i];
            dot += c * qk_s[i]; nn += c * c;
        }
        sims_s[tid] = dot / (fmaxf(sqrtf(nn), 1e-8f) * qn_s);
    }
    if (tid >= 64 && tid < 72) {
        int p = tid - 64, b = p >> 2, o = p & 3;
        float v = cb2[o];
        for (int j = 0; j < 64; ++j) v += ce_s[b * 64 + j] * cw2[o * 64 + j];
        sc_s[p] = v;
    }
    __syncthreads();
    if (tid == 0) {
        float bestv = -1e30f; int best = 0;
        for (int n = 0; n < NC_; ++n)
            if (sims_s[n] > bestv) { bestv = sims_s[n]; best = n; }
        flags[2] = (bestv >= 0.95f) ? 1 : 0;
        flags[3] = best;
        float bs = -1e30f; int bi = 0;
        for (int p = 0; p < 8; ++p)
            if (sc_s[p] > bs) { bs = sc_s[p]; bi = p; }
        flags[1] = bi & 3;
    }
}

// ---------------------------------------------------------------------------
// Scorer fp32 GEMM (precision-critical: feeds routing thresholds).
// Hp[kz][m][f] = sum over K-half kz of x[m,:] . sw1[f,:]
// Tile: BM=64, BN=128, BK=16, thread 4x8, 256 threads, grid (32,4,2).
// ---------------------------------------------------------------------------
__global__ __launch_bounds__(256) void scorer_gemm_kernel(
    const float* __restrict__ A, const float* __restrict__ Bw,
    float* __restrict__ Hp) {
    __shared__ float As[16][68];
    __shared__ float Bs[16][132];
    int m0 = blockIdx.x << 6, n0 = blockIdx.y << 7, kz = blockIdx.z;
    int tid = threadIdx.x;
    int ar = tid >> 2, ac = (tid & 3) << 2;
    int br = tid >> 1, bc = (tid & 1) << 3;
    const float* ap = A + (size_t)(m0 + ar) * H_ + ac;
    const float* bp = Bw + (size_t)(n0 + br) * H_ + bc;
    int ty = tid >> 4, tx = tid & 15;
    float acc[4][8];
#pragma unroll
    for (int i = 0; i < 4; ++i)
#pragma unroll
        for (int j = 0; j < 8; ++j) acc[i][j] = 0.f;

    int kbeg = kz << 10, kend = kbeg + 1024;
    for (int k0 = kbeg; k0 < kend; k0 += 16) {
        float4 a4 = *(const float4*)(ap + k0);
        float4 b4a = *(const float4*)(bp + k0);
        float4 b4b = *(const float4*)(bp + k0 + 4);
        __syncthreads();
        As[ac + 0][ar] = a4.x; As[ac + 1][ar] = a4.y;
        As[ac + 2][ar] = a4.z; As[ac + 3][ar] = a4.w;
        Bs[bc + 0][br] = b4a.x; Bs[bc + 1][br] = b4a.y;
        Bs[bc + 2][br] = b4a.z; Bs[bc + 3][br] = b4a.w;
        Bs[bc + 4][br] = b4b.x; Bs[bc + 5][br] = b4b.y;
        Bs[bc + 6][br] = b4b.z; Bs[bc + 7][br] = b4b.w;
        __syncthreads();
#pragma unroll
        for (int kk = 0; kk < 16; ++kk) {
            float4 a = *(const float4*)&As[kk][ty << 2];
            float4 b0 = *(const float4*)&Bs[kk][tx << 3];
            float4 b1 = *(const float4*)&Bs[kk][(tx << 3) + 4];
            float av[4] = {a.x, a.y, a.z, a.w};
            float bv[8] = {b0.x, b0.y, b0.z, b0.w, b1.x, b1.y, b1.z, b1.w};
#pragma unroll
            for (int i = 0; i < 4; ++i)
#pragma unroll
                for (int j = 0; j < 8; ++j) acc[i][j] += av[i] * bv[j];
        }
    }
    float* hp = Hp + (size_t)kz * M_ * F_;
#pragma unroll
    for (int i = 0; i < 4; ++i) {
        float* row = hp + (size_t)(m0 + (ty << 2) + i) * F_ + n0 + (tx << 3);
#pragma unroll
        for (int j = 0; j < 8; ++j) row[j] = acc[i][j];
    }
}

// ---------------------------------------------------------------------------
// score+route: content[m] = sum_f relu(hp0+hp1+b1[f]) * w2[f]; route + clist.
// 512 blocks x 256 threads, one wave per token.
// ---------------------------------------------------------------------------
__global__ __launch_bounds__(256) void score_route_kernel(
    const float* __restrict__ Hp, const float* __restrict__ b1,
    const float* __restrict__ w2, const float* __restrict__ b2,
    const float* __restrict__ pos,
    int* __restrict__ flags, int* __restrict__ route, int* __restrict__ clist) {
    int tid = threadIdx.x;
    int m = (blockIdx.x << 2) + (tid >> 6);
    int lane = tid & 63;
    const float* h0 = Hp + (size_t)m * F_;
    const float* h1 = Hp + (size_t)M_ * F_ + (size_t)m * F_;
    float s = 0.f;
    for (int f = lane; f < F_; f += 64) {
        float v = h0[f] + h1[f] + b1[f];
        s += fmaxf(v, 0.f) * w2[f];
    }
    for (int off = 32; off > 0; off >>= 1) s += __shfl_down(s, off, 64);
    if (lane == 0) {
        float content = s + b2[0];
        int si = m & (S_ - 1);
        float imp = 1.0f / (1.0f + expf(-(content + 0.1f * pos[si])));
        if (si == 0 || si == S_ - 1) imp *= 2.0f;
        int rt = (imp > 0.8f) ? 0 : ((imp < 0.3f) ? 1 : 2);
        route[m] = rt;
        if (rt == 0) {
            int idx = atomicAdd(&flags[0], 1);
            clist[idx] = m;
        }
    }
}

// ---------------------------------------------------------------------------
// bf16 MFMA NT GEMM: C[m,n] = sum_k A[m,k]*B[n,k] (+bias), fp32 in/out,
// in-kernel bf16 conversion. Tile 128x128, BK=32, 256 threads (4 waves 2x2),
// each wave 4x4 tiles of 16x16x32 MFMA. Optional gather rows / dynamic M /
// runtime-rank B select.
// ---------------------------------------------------------------------------
__global__ __launch_bounds__(256) void mfma_gemm_nt(
    const float* __restrict__ A,
    const float* __restrict__ B0, const float* __restrict__ B1,
    const float* __restrict__ B2, const float* __restrict__ B3,
    float* __restrict__ C, int M, int N, int K, int ldc,
    const float* __restrict__ bias,
    const int* __restrict__ gather, const int* __restrict__ count_ptr,
    const int* __restrict__ rank_ptr) {
    __shared__ ushort As[128][32];
    __shared__ ushort Bs[128][32];
    const float* Bp = B0;
    if (rank_ptr) {
        int r = *rank_ptr;
        Bp = (r == 0) ? B0 : (r == 1) ? B1 : (r == 2) ? B2 : B3;
        N  = (r == 0) ? 4  : (r == 1) ? 12  : (r == 2) ? 40  : 128;
    }
    if (count_ptr) M = *count_ptr;
    int m0 = blockIdx.x << 7, n0 = blockIdx.y << 7;
    if (m0 >= M) return;
    int tid = threadIdx.x;

    int sr = tid >> 3;           // 0..31 staging row-in-group
    int sc = (tid & 7) << 2;     // 0,4,..,28 staging col
    const float* aptr[4];
    const float* bptr[4];
    bool bval[4];
#pragma unroll
    for (int i = 0; i < 4; ++i) {
        int r = (i << 5) + sr;
        int am = m0 + r;
        int arow;
        if (am < M) arow = gather ? gather[am] : am;
        else        arow = gather ? gather[0]  : 0;
        aptr[i] = A + (size_t)arow * K + sc;
        int br = n0 + r;
        bval[i] = (br < N);
        bptr[i] = Bp + (size_t)(bval[i] ? br : 0) * K + sc;
    }

    int lane = tid & 63;
    int w = tid >> 6;
    int wm = (w >> 1) << 6, wn = (w & 1) << 6;
    int fr = lane & 15;
    int kb = (lane >> 4) << 3;

    f32x4 zero4 = {0.f, 0.f, 0.f, 0.f};
    f32x4 acc[4][4];
#pragma unroll
    for (int i = 0; i < 4; ++i)
#pragma unroll
        for (int j = 0; j < 4; ++j) acc[i][j] = zero4;

    for (int k0 = 0; k0 < K; k0 += 32) {
        float4 av[4], bv[4];
#pragma unroll
        for (int i = 0; i < 4; ++i) {
            av[i] = *(const float4*)(aptr[i] + k0);
            bv[i] = bval[i] ? *(const float4*)(bptr[i] + k0)
                            : make_float4(0.f, 0.f, 0.f, 0.f);
        }
        __syncthreads();
#pragma unroll
        for (int i = 0; i < 4; ++i) {
            int r = (i << 5) + sr;
            unsigned alo = (unsigned)f2bf(av[i].x) | ((unsigned)f2bf(av[i].y) << 16);
            unsigned ahi = (unsigned)f2bf(av[i].z) | ((unsigned)f2bf(av[i].w) << 16);
            unsigned blo = (unsigned)f2bf(bv[i].x) | ((unsigned)f2bf(bv[i].y) << 16);
            unsigned bhi = (unsigned)f2bf(bv[i].z) | ((unsigned)f2bf(bv[i].w) << 16);
            *(uint2*)&As[r][sc] = make_uint2(alo, ahi);
            *(uint2*)&Bs[r][sc] = make_uint2(blo, bhi);
        }
        __syncthreads();
        bf16x8 af[4], bf[4];
#pragma unroll
        for (int mt = 0; mt < 4; ++mt)
            af[mt] = *(const bf16x8*)&As[wm + (mt << 4) + fr][kb];
#pragma unroll
        for (int nt = 0; nt < 4; ++nt)
            bf[nt] = *(const bf16x8*)&Bs[wn + (nt << 4) + fr][kb];
#pragma unroll
        for (int mt = 0; mt < 4; ++mt)
#pragma unroll
            for (int nt = 0; nt < 4; ++nt)
                acc[mt][nt] = __builtin_amdgcn_mfma_f32_16x16x32_bf16(
                    af[mt], bf[nt], acc[mt][nt], 0, 0, 0);
    }

    int orr = (lane >> 4) << 2;
#pragma unroll
    for (int mt = 0; mt < 4; ++mt) {
#pragma unroll
        for (int r = 0; r < 4; ++r) {
            int m = m0 + wm + (mt << 4) + orr + r;
            if (m < M) {
                int orow = gather ? gather[m] : m;
                float* crow = C + (size_t)orow * ldc;
#pragma unroll
                for (int nt = 0; nt < 4; ++nt) {
                    int c = n0 + wn + (nt << 4) + fr;
                    if (c < N)
                        crow[c] = acc[mt][nt][r] + (bias ? bias[c] : 0.f);
                }
            }
        }
    }
}

// ---------------------------------------------------------------------------
// stage-2: low-rank apply + routing epilogue per class.
// cls==1 (simple): out = x + (hit ? cache_delta[best] : t4 @ v4^T)
// cls==2 (normal): out = x + tr @ v_rank^T
// ---------------------------------------------------------------------------
__global__ __launch_bounds__(256) void stage2_kernel(
    int cls, const float* __restrict__ x,
    const float* __restrict__ t4p, const float* __restrict__ trp,
    const float* __restrict__ v4, const float* __restrict__ v12,
    const float* __restrict__ v40, const float* __restrict__ v128,
    const float* __restrict__ cd, const int* __restrict__ flags,
    const int* __restrict__ route, float* __restrict__ out) {
    __shared__ float Ts[16][132];
    __shared__ int act[16];
    int tid = threadIdx.x;
    int m0 = blockIdx.x << 4;

    const float* V; int Kr; const float* T; int ldt;
    if (cls == 1) { V = v4; Kr = 4; T = t4p; ldt = 4; }
    else {
        int r = flags[1];
        V  = (r == 0) ? v4 : (r == 1) ? v12 : (r == 2) ? v40 : v128;
        Kr = (r == 0) ? 4  : (r == 1) ? 12  : (r == 2) ? 40  : 128;
        T = trp; ldt = 128;
    }
    int hit = flags[2], best = flags[3];

    if (tid < 16) act[tid] = (route[m0 + tid] == cls) ? 1 : 0;
    for (int idx = tid; idx < 16 * Kr; idx += 256) {
        int i = idx / Kr, j = idx - i * Kr;
        Ts[i][j] = T[(size_t)(m0 + i) * ldt + j];
    }
    __syncthreads();
    bool some = false;
#pragma unroll
    for (int i = 0; i < 16; ++i) some |= (act[i] != 0);
    if (!some) return;

    bool use_delta = (cls == 1) && hit;
    for (int c = tid; c < H_; c += 256) {
        float acc[16];
#pragma unroll
        for (int i = 0; i < 16; ++i) acc[i] = 0.f;
        if (!use_delta) {
            const float* vrow = V + (size_t)c * Kr;
            for (int j = 0; j < Kr; j += 4) {
                const float4 vv = *(const float4*)(vrow + j);
#pragma unroll
                for (int i = 0; i < 16; ++i) {
                    const float4 tv = *(const float4*)&Ts[i][j];
                    acc[i] += tv.x * vv.x + tv.y * vv.y + tv.z * vv.z + tv.w * vv.w;
                }
            }
        }
#pragma unroll
        for (int i = 0; i < 16; ++i) {
            if (act[i]) {
                size_t off = (size_t)(m0 + i) * H_ + c;
                float upd = use_delta
                    ? cd[(size_t)best * (size_t)(B_ * S_ * H_) + off]
                    : acc[i];
                out[off] = x[off] + upd;
            }
        }
    }
}

// ---------------------------------------------------------------------------
extern "C" void kernel_launch(void* const* d_in, const int* in_sizes, int n_in,
                              void* d_out, int out_size, void* d_ws, size_t ws_size,
                              hipStream_t stream) {
    const float* x    = (const float*)d_in[0];
    const float* sw1  = (const float*)d_in[1];
    const float* sb1  = (const float*)d_in[2];
    const float* sw2  = (const float*)d_in[3];
    const float* sb2  = (const float*)d_in[4];
    const float* pos  = (const float*)d_in[5];
    const float* kpw  = (const float*)d_in[6];
    const float* ck   = (const float*)d_in[7];
    const float* cd   = (const float*)d_in[8];
    const float* cw1  = (const float*)d_in[9];
    const float* cb1  = (const float*)d_in[10];
    const float* cw2  = (const float*)d_in[11];
    const float* cb2  = (const float*)d_in[12];
    const float* u4   = (const float*)d_in[13];
    const float* v4   = (const float*)d_in[14];
    const float* u12  = (const float*)d_in[15];
    const float* v12  = (const float*)d_in[16];
    const float* u40  = (const float*)d_in[17];
    const float* v40  = (const float*)d_in[18];
    const float* u128 = (const float*)d_in[19];
    const float* v128 = (const float*)d_in[20];
    const float* lw   = (const float*)d_in[21];
    const float* lb   = (const float*)d_in[22];
    float* out = (float*)d_out;

    // workspace layout (~1.38 MB, same scale as round 1)
    float* wsf   = (float*)d_ws;
    float* xp    = wsf;                        // [B,H]      4096
    float* t4p   = xp + B_ * H_;               // [M,4]      8192
    float* trp   = t4p + M_ * 4;               // [M,128]    262144
    int*   flags = (int*)(trp + M_ * 128);     // 8 ints
    int*   route = flags + 8;                  // [M]
    int*   clist = route + M_;                 // [M]
    float* partial = (float*)(clist + M_);     // [32,H] = 65536
    // scorer K-split partials live in d_out's first 8.4 MB: consumed by
    // score_route before any output row is written; afterwards every output
    // element is written by exactly one of {crit mfma, stage2 cls1/2}.
    float* hpart = out;

    hipMemsetAsync(flags, 0, sizeof(int), stream);   // n_crit = 0

    pool_partial_kernel<<<256, 256, 0, stream>>>(x, partial);
    pool_final_kernel<<<16, 256, 0, stream>>>(partial, xp);
    decide_kernel<<<1, 256, 0, stream>>>(xp, kpw, ck, cw1, cb1, cw2, cb2, flags);

    // scorer: Hp[2][M][F] = K-split x @ sw1^T (fp32, routing-critical)
    scorer_gemm_kernel<<<dim3(32, 4, 2), 256, 0, stream>>>(x, sw1, hpart);
    score_route_kernel<<<512, 256, 0, stream>>>(hpart, sb1, sw2, sb2, pos,
                                                flags, route, clist);

    // critical rows (gathered, dynamic M): out[row] = x[row] @ lw^T + lb
    mfma_gemm_nt<<<dim3(16, 16), 256, 0, stream>>>(
        x, lw, nullptr, nullptr, nullptr, out, M_, H_, H_, H_,
        lb, clist, &flags[0], nullptr);

    // t4 = x @ u4^T  [M,4]
    mfma_gemm_nt<<<dim3(16, 1), 256, 0, stream>>>(
        x, u4, nullptr, nullptr, nullptr, t4p, M_, 4, H_, 4,
        nullptr, nullptr, nullptr, nullptr);

    // tr = x @ u_rank^T  [M,r] (rank selected on device)
    mfma_gemm_nt<<<dim3(16, 1), 256, 0, stream>>>(
        x, u4, u12, u40, u128, trp, M_, 128, H_, 128,
        nullptr, nullptr, nullptr, &flags[1]);

    // simple rows
    stage2_kernel<<<128, 256, 0, stream>>>(
        1, x, t4p, trp, v4, v12, v40, v128, cd, flags, route, out);
    // normal rows
    stage2_kernel<<<128, 256, 0, stream>>>(
        2, x, t4p, trp, v4, v12, v40, v128, cd, flags, route, out);
}